// Round 1
// baseline (267.100 us; speedup 1.0000x reference)
//
#include <hip/hip_runtime.h>
#include <hip/hip_bf16.h>

typedef __attribute__((ext_vector_type(8))) short bf16x8;
typedef __attribute__((ext_vector_type(4))) float f32x4;

#define NB 8
#define NN 2048
#define DM 512
#define DF 1024

__device__ __forceinline__ ushort f2b(float f) {
  union { __hip_bfloat16 h; ushort u; } c;
  c.h = __float2bfloat16(f);
  return c.u;
}

typedef __attribute__((address_space(1))) const void gvoid_t;
typedef __attribute__((address_space(3))) void svoid_t;
__device__ __forceinline__ void gload16(const void* g, void* s) {
  __builtin_amdgcn_global_load_lds((gvoid_t*)g, (svoid_t*)s, 16, 0, 0);
}

// ---------------- NT GEMM core ----------------
// C[128x128] = A[128 rows of K] * B[128 rows of K]^T ; bf16 inputs, fp32 acc.
// BK=64 (128B rows in LDS). XOR swizzle: LDS slot (row, c16) holds global
// 16B-chunk (c16 ^ (row&7)) -- applied on the global source address during
// global_load_lds staging (linear LDS dest) and on the ds_read address.
__device__ __forceinline__ void gemm_core_128(
    const ushort* __restrict__ A, const ushort* __restrict__ B,
    int K, int brow, int bcol, f32x4 (&acc)[4][4])
{
  __shared__ ushort As[128 * 64];
  __shared__ ushort Bs[128 * 64];
  const int tid = threadIdx.x;
  const int w = tid >> 6;
  const int l = tid & 63;
  // staging: issue i covers rows i*32 .. i*32+31; wave w covers 8 rows.
  const int sr = (w << 3) + (l >> 3);            // + i*32
  const int sc = (((l & 7) ^ (l >> 3)) << 3);    // swizzled source chunk (elements)
  char* AsB = (char*)As;
  char* BsB = (char*)Bs;
  const int fr = l & 15;
  const int arow = ((w >> 1) << 6) + fr;         // + m*16
  const int brw  = ((w & 1) << 6) + fr;          // + n*16

#pragma unroll
  for (int m = 0; m < 4; m++)
#pragma unroll
    for (int n = 0; n < 4; n++)
      acc[m][n] = (f32x4){0.f, 0.f, 0.f, 0.f};

  const ushort* Ap = A + (long)(brow + sr) * K + sc;
  const ushort* Bp = B + (long)(bcol + sr) * K + sc;
  const int nkt = K >> 6;
  for (int kt = 0; kt < nkt; ++kt) {
#pragma unroll
    for (int i = 0; i < 4; i++) {
      gload16(Ap + (long)i * 32 * K, AsB + i * 4096 + (w << 10));
      gload16(Bp + (long)i * 32 * K, BsB + i * 4096 + (w << 10));
    }
    Ap += 64; Bp += 64;
    __syncthreads();
#pragma unroll
    for (int kk = 0; kk < 2; kk++) {
      const int cx = ((((kk << 2) + (l >> 4)) ^ (l & 7)) << 4);  // swizzled byte chunk
      bf16x8 a[4], b[4];
#pragma unroll
      for (int m = 0; m < 4; m++)
        a[m] = *(const bf16x8*)(AsB + (arow + m * 16) * 128 + cx);
#pragma unroll
      for (int n = 0; n < 4; n++)
        b[n] = *(const bf16x8*)(BsB + (brw + n * 16) * 128 + cx);
#pragma unroll
      for (int m = 0; m < 4; m++)
#pragma unroll
        for (int n = 0; n < 4; n++)
          acc[m][n] = __builtin_amdgcn_mfma_f32_16x16x32_bf16(a[m], b[n], acc[m][n], 0, 0, 0);
    }
    __syncthreads();
  }
}

// ---------------- kernels ----------------

__global__ __launch_bounds__(256) void k_cvt(const float* __restrict__ in,
                                             ushort* __restrict__ out) {
  const long i = ((long)blockIdx.x * 256 + threadIdx.x) << 2;
  const float4 v = *(const float4*)(in + i);
  ushort4 o;
  o.x = f2b(v.x); o.y = f2b(v.y); o.z = f2b(v.z); o.w = f2b(v.w);
  *(ushort4*)(out + i) = o;
}

__device__ __forceinline__ float ld2f(const float* p, long i) { return p[i]; }
__device__ __forceinline__ float ld2f(const __hip_bfloat16* p, long i) { return __bfloat162float(p[i]); }

// out[C][R] = (bf16) in[R][C], batched via blockIdx.z
template <typename TIN>
__global__ __launch_bounds__(256) void k_tr(const TIN* __restrict__ in, ushort* __restrict__ out,
                                            int R, int C, long inB, long outB) {
  __shared__ float t[32][33];
  const long b = blockIdx.z;
  const TIN* ip = in + b * inB;
  ushort* op = out + b * outB;
  const int c0 = blockIdx.x << 5, r0 = blockIdx.y << 5;
  const int tx = threadIdx.x & 31, ty = threadIdx.x >> 5;  // 32x8
#pragma unroll
  for (int j = 0; j < 32; j += 8)
    t[ty + j][tx] = ld2f(ip, (long)(r0 + ty + j) * C + (c0 + tx));
  __syncthreads();
#pragma unroll
  for (int j = 0; j < 32; j += 8)
    op[(long)(c0 + ty + j) * R + (r0 + tx)] = f2b(t[tx][ty + j]);
}

__global__ __launch_bounds__(256) void k_gemm1(const ushort* __restrict__ xb,
                                               const ushort* __restrict__ w1t,
                                               const float* __restrict__ b1,
                                               ushort* __restrict__ hb) {
  f32x4 acc[4][4];
  const int brow = blockIdx.x << 7, bcol = blockIdx.y << 7;
  gemm_core_128(xb, w1t, DM, brow, bcol, acc);
  const int tid = threadIdx.x, w = tid >> 6, l = tid & 63;
  const int r0 = brow + ((w >> 1) << 6) + ((l >> 4) << 2);
  const int c0 = bcol + ((w & 1) << 6) + (l & 15);
#pragma unroll
  for (int n = 0; n < 4; n++) {
    const int c = c0 + n * 16;
    const float bias = b1[c];
#pragma unroll
    for (int m = 0; m < 4; m++) {
      const int r = r0 + m * 16;
#pragma unroll
      for (int j = 0; j < 4; j++) {
        float v = acc[m][n][j] + bias;
        hb[(long)(r + j) * DF + c] = f2b(v > 0.f ? v : 0.f);
      }
    }
  }
}

__global__ __launch_bounds__(256) void k_gemm2(const ushort* __restrict__ hb,
                                               const ushort* __restrict__ w2t,
                                               const float* __restrict__ b2,
                                               ushort* __restrict__ kb,
                                               ushort* __restrict__ qb,
                                               ushort* __restrict__ vb) {
  f32x4 acc[4][4];
  const int brow = blockIdx.x << 7, bcol = blockIdx.y << 7;
  gemm_core_128(hb, w2t, DF, brow, bcol, acc);
  const int seg = bcol >> 9;  // 0:k 1:q 2:v (reference splits k first!)
  ushort* dst = (seg == 0) ? kb : ((seg == 1) ? qb : vb);
  const int tid = threadIdx.x, w = tid >> 6, l = tid & 63;
  const int r0 = brow + ((w >> 1) << 6) + ((l >> 4) << 2);
  const int c0 = bcol + ((w & 1) << 6) + (l & 15);
#pragma unroll
  for (int n = 0; n < 4; n++) {
    const int c = c0 + n * 16;
    const float bias = b2[c];
    const int cl = c - (seg << 9);
#pragma unroll
    for (int m = 0; m < 4; m++) {
      const int r = r0 + m * 16;
#pragma unroll
      for (int j = 0; j < 4; j++)
        dst[(long)(r + j) * DM + cl] = f2b(acc[m][n][j] + bias);
    }
  }
}

__global__ __launch_bounds__(256) void k_qk(const ushort* __restrict__ qb,
                                            const ushort* __restrict__ kb,
                                            const float* __restrict__ mask,
                                            ushort* __restrict__ Sbuf, int b0) {
  const int z = blockIdx.z, batch = b0 + z;
  const ushort* A = qb + (long)batch * NN * DM;
  const ushort* Bm = kb + (long)batch * NN * DM;
  const float* mk = mask + (long)batch * NN * NN;
  ushort* S = Sbuf + (long)z * NN * NN;
  f32x4 acc[4][4];
  const int brow = blockIdx.x << 7, bcol = blockIdx.y << 7;
  gemm_core_128(A, Bm, DM, brow, bcol, acc);
  const float scale = 0.04419417382415922f;  // 1/sqrt(512)
  const int tid = threadIdx.x, w = tid >> 6, l = tid & 63;
  const int r0 = brow + ((w >> 1) << 6) + ((l >> 4) << 2);
  const int c0 = bcol + ((w & 1) << 6) + (l & 15);
#pragma unroll
  for (int n = 0; n < 4; n++) {
    const int c = c0 + n * 16;
#pragma unroll
    for (int m = 0; m < 4; m++) {
      const int r = r0 + m * 16;
#pragma unroll
      for (int j = 0; j < 4; j++) {
        const float mv = mk[(long)(r + j) * NN + c];
        S[(long)(r + j) * NN + c] = f2b(acc[m][n][j] * scale * mv);
      }
    }
  }
}

__global__ __launch_bounds__(256) void k_pv(const ushort* __restrict__ Sbuf,
                                            const ushort* __restrict__ vtb,
                                            float* __restrict__ out, int b0) {
  const int z = blockIdx.z, batch = b0 + z;
  const ushort* A = Sbuf + (long)z * NN * NN;
  const ushort* Bm = vtb + (long)batch * DM * NN;  // v^T [512][2048]
  float* op = out + (long)batch * NN * DM;
  f32x4 acc[4][4];
  const int brow = blockIdx.x << 7, bcol = blockIdx.y << 7;
  gemm_core_128(A, Bm, NN, brow, bcol, acc);
  const int tid = threadIdx.x, w = tid >> 6, l = tid & 63;
  const int r0 = brow + ((w >> 1) << 6) + ((l >> 4) << 2);
  const int c0 = bcol + ((w & 1) << 6) + (l & 15);
#pragma unroll
  for (int n = 0; n < 4; n++) {
    const int c = c0 + n * 16;
#pragma unroll
    for (int m = 0; m < 4; m++) {
      const int r = r0 + m * 16;
#pragma unroll
      for (int j = 0; j < 4; j++)
        op[(long)(r + j) * DM + c] = acc[m][n][j];
    }
  }
}

// ---------------- launch ----------------
extern "C" void kernel_launch(void* const* d_in, const int* in_sizes, int n_in,
                              void* d_out, int out_size, void* d_ws, size_t ws_size,
                              hipStream_t stream) {
  const float* x    = (const float*)d_in[0];
  const float* mask = (const float*)d_in[1];
  const float* W1   = (const float*)d_in[2];
  const float* b1   = (const float*)d_in[3];
  const float* W2   = (const float*)d_in[4];
  const float* b2   = (const float*)d_in[5];
  float* out = (float*)d_out;

  char* ws = (char*)d_ws;
  size_t off = 0;
  auto alloc = [&](size_t n) { char* p = ws + off; off += (n + 255) & ~(size_t)255; return p; };
  ushort* xb  = (ushort*)alloc((size_t)NB * NN * DM * 2);  // dead after gemm1
  ushort* hb  = (ushort*)alloc((size_t)NB * NN * DF * 2);  // dead after gemm2
  ushort* w1t = (ushort*)alloc((size_t)DF * DM * 2);
  ushort* w2t = (ushort*)alloc((size_t)3 * DM * DF * 2);
  ushort* kb  = (ushort*)alloc((size_t)NB * NN * DM * 2);
  ushort* qb  = (ushort*)alloc((size_t)NB * NN * DM * 2);
  ushort* vb  = (ushort*)alloc((size_t)NB * NN * DM * 2);
  ushort* vtb = (ushort*)alloc((size_t)NB * NN * DM * 2);
  // S for 4 batches overlaps dead xb+hb region (33.5MB <= 50.3MB)
  ushort* Sbuf = (ushort*)ws;

  // x -> bf16  (8 * 2048 * 512 / (4*256) = 8192 blocks, exact)
  k_cvt<<<dim3(8192), dim3(256), 0, stream>>>(x, xb);
  // W1 [512,1024] -> w1t [1024,512] ; W2 [1024,1536] -> w2t [1536,1024]
  k_tr<float><<<dim3(DF / 32, DM / 32, 1), dim3(256), 0, stream>>>(W1, w1t, DM, DF, 0, 0);
  k_tr<float><<<dim3(3 * DM / 32, DF / 32, 1), dim3(256), 0, stream>>>(W2, w2t, DF, 3 * DM, 0, 0);
  // h = relu(x@W1+b1)
  k_gemm1<<<dim3(NB * NN / 128, DF / 128), dim3(256), 0, stream>>>(xb, w1t, b1, hb);
  // kqv = h@W2+b2, split
  k_gemm2<<<dim3(NB * NN / 128, 3 * DM / 128), dim3(256), 0, stream>>>(hb, w2t, b2, kb, qb, vb);
  // v [2048,512] -> v^T [512,2048] per batch
  k_tr<__hip_bfloat16><<<dim3(DM / 32, NN / 32, NB), dim3(256), 0, stream>>>(
      (const __hip_bfloat16*)vb, vtb, NN, DM, (long)NN * DM, (long)DM * NN);
  // attention, 4 batches per group (S reuses dead ws region)
  for (int g = 0; g < NB; g += 4) {
    k_qk<<<dim3(NN / 128, NN / 128, 4), dim3(256), 0, stream>>>(qb, kb, mask, Sbuf, g);
    k_pv<<<dim3(NN / 128, DM / 128, 4), dim3(256), 0, stream>>>(Sbuf, vtb, out, g);
  }
}

// Round 2
// 232.363 us; speedup vs baseline: 1.1495x; 1.1495x over previous
//
#include <hip/hip_runtime.h>
#include <hip/hip_bf16.h>

typedef __attribute__((ext_vector_type(8))) short bf16x8;
typedef __attribute__((ext_vector_type(4))) float f32x4;

#define NB 8
#define NN 2048
#define DM 512
#define DF 1024

__device__ __forceinline__ ushort f2b(float f) {
  union { __hip_bfloat16 h; ushort u; } c;
  c.h = __float2bfloat16(f);
  return c.u;
}

typedef __attribute__((address_space(1))) const void gvoid_t;
typedef __attribute__((address_space(3))) void svoid_t;
__device__ __forceinline__ void gload16(const void* g, void* s) {
  __builtin_amdgcn_global_load_lds((gvoid_t*)g, (svoid_t*)s, 16, 0, 0);
}

// ---------------- NT GEMM core ----------------
// C[128x128] = A[128 rows of K] * B[128 rows of K]^T ; bf16 inputs, fp32 acc.
// BK=64 (128B rows in LDS). XOR swizzle: LDS slot (row, c16) holds global
// 16B-chunk (c16 ^ (row&7)) -- applied on the global source address during
// global_load_lds staging (linear LDS dest) and on the ds_read address.
__device__ __forceinline__ void gemm_core_128(
    const ushort* __restrict__ A, const ushort* __restrict__ B,
    int K, int brow, int bcol, f32x4 (&acc)[4][4])
{
  __shared__ ushort As[128 * 64];
  __shared__ ushort Bs[128 * 64];
  const int tid = threadIdx.x;
  const int w = tid >> 6;
  const int l = tid & 63;
  // staging: issue i covers rows i*32 .. i*32+31; wave w covers 8 rows.
  const int sr = (w << 3) + (l >> 3);            // + i*32
  const int sc = (((l & 7) ^ (l >> 3)) << 3);    // swizzled source chunk (elements)
  char* AsB = (char*)As;
  char* BsB = (char*)Bs;
  const int fr = l & 15;
  const int arow = ((w >> 1) << 6) + fr;         // + m*16
  const int brw  = ((w & 1) << 6) + fr;          // + n*16

#pragma unroll
  for (int m = 0; m < 4; m++)
#pragma unroll
    for (int n = 0; n < 4; n++)
      acc[m][n] = (f32x4){0.f, 0.f, 0.f, 0.f};

  const ushort* Ap = A + (long)(brow + sr) * K + sc;
  const ushort* Bp = B + (long)(bcol + sr) * K + sc;
  const int nkt = K >> 6;
  for (int kt = 0; kt < nkt; ++kt) {
#pragma unroll
    for (int i = 0; i < 4; i++) {
      gload16(Ap + (long)i * 32 * K, AsB + i * 4096 + (w << 10));
      gload16(Bp + (long)i * 32 * K, BsB + i * 4096 + (w << 10));
    }
    Ap += 64; Bp += 64;
    __syncthreads();
#pragma unroll
    for (int kk = 0; kk < 2; kk++) {
      const int cx = ((((kk << 2) + (l >> 4)) ^ (l & 7)) << 4);  // swizzled byte chunk
      bf16x8 a[4], b[4];
#pragma unroll
      for (int m = 0; m < 4; m++)
        a[m] = *(const bf16x8*)(AsB + (arow + m * 16) * 128 + cx);
#pragma unroll
      for (int n = 0; n < 4; n++)
        b[n] = *(const bf16x8*)(BsB + (brw + n * 16) * 128 + cx);
#pragma unroll
      for (int m = 0; m < 4; m++)
#pragma unroll
        for (int n = 0; n < 4; n++)
          acc[m][n] = __builtin_amdgcn_mfma_f32_16x16x32_bf16(a[m], b[n], acc[m][n], 0, 0, 0);
    }
    __syncthreads();
  }
}

// ---------------- kernels ----------------

__global__ __launch_bounds__(256) void k_cvt(const float* __restrict__ in,
                                             ushort* __restrict__ out) {
  const long i = ((long)blockIdx.x * 256 + threadIdx.x) << 2;
  const float4 v = *(const float4*)(in + i);
  ushort4 o;
  o.x = f2b(v.x); o.y = f2b(v.y); o.z = f2b(v.z); o.w = f2b(v.w);
  *(ushort4*)(out + i) = o;
}

__device__ __forceinline__ float ld2f(const float* p, long i) { return p[i]; }
__device__ __forceinline__ float ld2f(const __hip_bfloat16* p, long i) { return __bfloat162float(p[i]); }

// out[C][R] = (bf16) in[R][C], batched via blockIdx.z
template <typename TIN>
__global__ __launch_bounds__(256) void k_tr(const TIN* __restrict__ in, ushort* __restrict__ out,
                                            int R, int C, long inB, long outB) {
  __shared__ float t[32][33];
  const long b = blockIdx.z;
  const TIN* ip = in + b * inB;
  ushort* op = out + b * outB;
  const int c0 = blockIdx.x << 5, r0 = blockIdx.y << 5;
  const int tx = threadIdx.x & 31, ty = threadIdx.x >> 5;  // 32x8
#pragma unroll
  for (int j = 0; j < 32; j += 8)
    t[ty + j][tx] = ld2f(ip, (long)(r0 + ty + j) * C + (c0 + tx));
  __syncthreads();
#pragma unroll
  for (int j = 0; j < 32; j += 8)
    op[(long)(c0 + ty + j) * R + (r0 + tx)] = f2b(t[tx][ty + j]);
}

__global__ __launch_bounds__(256) void k_gemm1(const ushort* __restrict__ xb,
                                               const ushort* __restrict__ w1t,
                                               const float* __restrict__ b1,
                                               ushort* __restrict__ hb) {
  f32x4 acc[4][4];
  const int brow = blockIdx.x << 7, bcol = blockIdx.y << 7;
  gemm_core_128(xb, w1t, DM, brow, bcol, acc);
  const int tid = threadIdx.x, w = tid >> 6, l = tid & 63;
  const int r0 = brow + ((w >> 1) << 6) + ((l >> 4) << 2);
  const int c0 = bcol + ((w & 1) << 6) + (l & 15);
#pragma unroll
  for (int n = 0; n < 4; n++) {
    const int c = c0 + n * 16;
    const float bias = b1[c];
#pragma unroll
    for (int m = 0; m < 4; m++) {
      const int r = r0 + m * 16;
#pragma unroll
      for (int j = 0; j < 4; j++) {
        float v = acc[m][n][j] + bias;
        hb[(long)(r + j) * DF + c] = f2b(v > 0.f ? v : 0.f);
      }
    }
  }
}

__global__ __launch_bounds__(256) void k_gemm2(const ushort* __restrict__ hb,
                                               const ushort* __restrict__ w2t,
                                               const float* __restrict__ b2,
                                               ushort* __restrict__ kb,
                                               ushort* __restrict__ qb,
                                               ushort* __restrict__ vb) {
  f32x4 acc[4][4];
  const int brow = blockIdx.x << 7, bcol = blockIdx.y << 7;
  gemm_core_128(hb, w2t, DF, brow, bcol, acc);
  const int seg = bcol >> 9;  // 0:k 1:q 2:v (reference splits k first!)
  ushort* dst = (seg == 0) ? kb : ((seg == 1) ? qb : vb);
  // fold attn scale = 1/sqrt(512) into q
  const float sc = (seg == 1) ? 0.04419417382415922f : 1.0f;
  const int tid = threadIdx.x, w = tid >> 6, l = tid & 63;
  const int r0 = brow + ((w >> 1) << 6) + ((l >> 4) << 2);
  const int c0 = bcol + ((w & 1) << 6) + (l & 15);
#pragma unroll
  for (int n = 0; n < 4; n++) {
    const int c = c0 + n * 16;
    const float bias = b2[c];
    const int cl = c - (seg << 9);
#pragma unroll
    for (int m = 0; m < 4; m++) {
      const int r = r0 + m * 16;
#pragma unroll
      for (int j = 0; j < 4; j++)
        dst[(long)(r + j) * DM + cl] = f2b((acc[m][n][j] + bias) * sc);
    }
  }
}

__global__ __launch_bounds__(256) void k_qk(const ushort* __restrict__ qb,
                                            const ushort* __restrict__ kb,
                                            const float* __restrict__ mask,
                                            ushort* __restrict__ Sbuf) {
  const int batch = blockIdx.z;
  const ushort* A = qb + (long)batch * NN * DM;
  const ushort* Bm = kb + (long)batch * NN * DM;
  const float* mk = mask + (long)batch * NN * NN;
  ushort* S = Sbuf + (long)batch * NN * NN;
  f32x4 acc[4][4];
  const int brow = blockIdx.x << 7, bcol = blockIdx.y << 7;
  gemm_core_128(A, Bm, DM, brow, bcol, acc);
  const int tid = threadIdx.x, w = tid >> 6, l = tid & 63;
  const int r0 = brow + ((w >> 1) << 6) + ((l >> 4) << 2);
  const int c0 = bcol + ((w & 1) << 6) + (l & 15);
#pragma unroll
  for (int n = 0; n < 4; n++) {
    const int c = c0 + n * 16;
#pragma unroll
    for (int m = 0; m < 4; m++) {
      const int r = r0 + m * 16;
#pragma unroll
      for (int j = 0; j < 4; j++) {
        const float mv = mk[(long)(r + j) * NN + c];
        S[(long)(r + j) * NN + c] = f2b(acc[m][n][j] * mv);
      }
    }
  }
}

__global__ __launch_bounds__(256) void k_pv(const ushort* __restrict__ Sbuf,
                                            const ushort* __restrict__ vtb,
                                            float* __restrict__ out) {
  const int batch = blockIdx.z;
  const ushort* A = Sbuf + (long)batch * NN * NN;
  const ushort* Bm = vtb + (long)batch * DM * NN;  // v^T [512][2048]
  float* op = out + (long)batch * NN * DM;
  f32x4 acc[4][4];
  const int brow = blockIdx.x << 7, bcol = blockIdx.y << 7;
  gemm_core_128(A, Bm, NN, brow, bcol, acc);
  const int tid = threadIdx.x, w = tid >> 6, l = tid & 63;
  const int r0 = brow + ((w >> 1) << 6) + ((l >> 4) << 2);
  const int c0 = bcol + ((w & 1) << 6) + (l & 15);
#pragma unroll
  for (int n = 0; n < 4; n++) {
    const int c = c0 + n * 16;
#pragma unroll
    for (int m = 0; m < 4; m++) {
      const int r = r0 + m * 16;
#pragma unroll
      for (int j = 0; j < 4; j++)
        op[(long)(r + j) * DM + c] = acc[m][n][j];
    }
  }
}

// ---------------- launch ----------------
extern "C" void kernel_launch(void* const* d_in, const int* in_sizes, int n_in,
                              void* d_out, int out_size, void* d_ws, size_t ws_size,
                              hipStream_t stream) {
  const float* x    = (const float*)d_in[0];
  const float* mask = (const float*)d_in[1];
  const float* W1   = (const float*)d_in[2];
  const float* b1   = (const float*)d_in[3];
  const float* W2   = (const float*)d_in[4];
  const float* b2   = (const float*)d_in[5];
  float* out = (float*)d_out;

  char* ws = (char*)d_ws;
  size_t off = 0;
  auto alloc = [&](size_t n) { char* p = ws + off; off += (n + 255) & ~(size_t)255; return p; };
  ushort* xb  = (ushort*)alloc((size_t)NB * NN * DM * 2);
  ushort* hb  = (ushort*)alloc((size_t)NB * NN * DF * 2);
  ushort* w1t = (ushort*)alloc((size_t)DF * DM * 2);
  ushort* w2t = (ushort*)alloc((size_t)3 * DM * DF * 2);
  ushort* kb  = (ushort*)alloc((size_t)NB * NN * DM * 2);
  ushort* qb  = (ushort*)alloc((size_t)NB * NN * DM * 2);
  ushort* vb  = (ushort*)alloc((size_t)NB * NN * DM * 2);
  ushort* vtb = (ushort*)alloc((size_t)NB * NN * DM * 2);
  ushort* Sbuf = (ushort*)alloc((size_t)NB * NN * NN * 2);  // full 8-batch S (67MB)

  // x -> bf16  (8 * 2048 * 512 / (4*256) = 8192 blocks, exact)
  k_cvt<<<dim3(8192), dim3(256), 0, stream>>>(x, xb);
  // W1 [512,1024] -> w1t [1024,512] ; W2 [1024,1536] -> w2t [1536,1024]
  k_tr<float><<<dim3(DF / 32, DM / 32, 1), dim3(256), 0, stream>>>(W1, w1t, DM, DF, 0, 0);
  k_tr<float><<<dim3(3 * DM / 32, DF / 32, 1), dim3(256), 0, stream>>>(W2, w2t, DF, 3 * DM, 0, 0);
  // h = relu(x@W1+b1)
  k_gemm1<<<dim3(NB * NN / 128, DF / 128), dim3(256), 0, stream>>>(xb, w1t, b1, hb);
  // kqv = h@W2+b2, split (q pre-scaled)
  k_gemm2<<<dim3(NB * NN / 128, 3 * DM / 128), dim3(256), 0, stream>>>(hb, w2t, b2, kb, qb, vb);
  // v [2048,512] -> v^T [512,2048] per batch
  k_tr<__hip_bfloat16><<<dim3(DM / 32, NN / 32, NB), dim3(256), 0, stream>>>(
      (const __hip_bfloat16*)vb, vtb, NN, DM, (long)NN * DM, (long)DM * NN);
  // attention: all 8 batches in single launches
  k_qk<<<dim3(NN / 128, NN / 128, NB), dim3(256), 0, stream>>>(qb, kb, mask, Sbuf);
  k_pv<<<dim3(NN / 128, DM / 128, NB), dim3(256), 0, stream>>>(Sbuf, vtb, out);
}

// Round 3
// 222.943 us; speedup vs baseline: 1.1981x; 1.0423x over previous
//
#include <hip/hip_runtime.h>
#include <hip/hip_bf16.h>

typedef __attribute__((ext_vector_type(8))) short bf16x8;
typedef __attribute__((ext_vector_type(4))) float f32x4;

#define NB 8
#define NN 2048
#define DM 512
#define DF 1024

__device__ __forceinline__ ushort f2b(float f) {
  union { __hip_bfloat16 h; ushort u; } c;
  c.h = __float2bfloat16(f);
  return c.u;
}
__device__ __forceinline__ float b2f(ushort u) {
  union { ushort u; __hip_bfloat16 h; } c;
  c.u = u;
  return __bfloat162float(c.h);
}

typedef __attribute__((address_space(1))) const void gvoid_t;
typedef __attribute__((address_space(3))) void svoid_t;
__device__ __forceinline__ void gload16(const void* g, void* s) {
  __builtin_amdgcn_global_load_lds((gvoid_t*)g, (svoid_t*)s, 16, 0, 0);
}

// ---------------- NT GEMM core ----------------
// C[128x128] = A[128 rows of K] * B[128 rows of K]^T ; bf16 in, fp32 acc.
// BK=64 (128B rows in LDS). XOR swizzle on global source + ds_read addr.
// smem: 128*128 ushort; core uses [0,8192) for As, [8192,16384) for Bs.
// Ends with __syncthreads() -> caller may immediately reuse smem.
__device__ __forceinline__ void gemm_core_128(
    const ushort* __restrict__ A, const ushort* __restrict__ B,
    int K, int brow, int bcol, f32x4 (&acc)[4][4], ushort* smem)
{
  ushort* As = smem;
  ushort* Bs = smem + 128 * 64;
  const int tid = threadIdx.x;
  const int w = tid >> 6;
  const int l = tid & 63;
  const int sr = (w << 3) + (l >> 3);            // + i*32
  const int sc = (((l & 7) ^ (l >> 3)) << 3);    // swizzled source chunk (elements)
  char* AsB = (char*)As;
  char* BsB = (char*)Bs;
  const int fr = l & 15;
  const int arow = ((w >> 1) << 6) + fr;         // + m*16
  const int brw  = ((w & 1) << 6) + fr;          // + n*16

#pragma unroll
  for (int m = 0; m < 4; m++)
#pragma unroll
    for (int n = 0; n < 4; n++)
      acc[m][n] = (f32x4){0.f, 0.f, 0.f, 0.f};

  const ushort* Ap = A + (long)(brow + sr) * K + sc;
  const ushort* Bp = B + (long)(bcol + sr) * K + sc;
  const int nkt = K >> 6;
  for (int kt = 0; kt < nkt; ++kt) {
#pragma unroll
    for (int i = 0; i < 4; i++) {
      gload16(Ap + (long)i * 32 * K, AsB + i * 4096 + (w << 10));
      gload16(Bp + (long)i * 32 * K, BsB + i * 4096 + (w << 10));
    }
    Ap += 64; Bp += 64;
    __syncthreads();
#pragma unroll
    for (int kk = 0; kk < 2; kk++) {
      const int cx = ((((kk << 2) + (l >> 4)) ^ (l & 7)) << 4);  // swizzled byte chunk
      bf16x8 a[4], b[4];
#pragma unroll
      for (int m = 0; m < 4; m++)
        a[m] = *(const bf16x8*)(AsB + (arow + m * 16) * 128 + cx);
#pragma unroll
      for (int n = 0; n < 4; n++)
        b[n] = *(const bf16x8*)(BsB + (brw + n * 16) * 128 + cx);
#pragma unroll
      for (int m = 0; m < 4; m++)
#pragma unroll
        for (int n = 0; n < 4; n++)
          acc[m][n] = __builtin_amdgcn_mfma_f32_16x16x32_bf16(a[m], b[n], acc[m][n], 0, 0, 0);
    }
    __syncthreads();
  }
}

// Write acc (already post-processed, bf16 values) into LDS at tile-local
// (row,col). smem reused as 128x128 bf16.
__device__ __forceinline__ void acc_to_lds_bf16(f32x4 (&acc)[4][4], ushort* smem) {
  const int tid = threadIdx.x, w = tid >> 6, l = tid & 63;
  const int r0l = ((w >> 1) << 6) + ((l >> 4) << 2);
  const int c0l = ((w & 1) << 6) + (l & 15);
#pragma unroll
  for (int n = 0; n < 4; n++)
#pragma unroll
    for (int m = 0; m < 4; m++)
#pragma unroll
      for (int j = 0; j < 4; j++)
        smem[(r0l + m * 16 + j) * 128 + (c0l + n * 16)] = f2b(acc[m][n][j]);
}

// ---------------- kernels ----------------

__global__ __launch_bounds__(256) void k_cvt(const float* __restrict__ in,
                                             ushort* __restrict__ out) {
  const long i = ((long)blockIdx.x * 256 + threadIdx.x) << 2;
  const float4 v = *(const float4*)(in + i);
  ushort4 o;
  o.x = f2b(v.x); o.y = f2b(v.y); o.z = f2b(v.z); o.w = f2b(v.w);
  *(ushort4*)(out + i) = o;
}

__device__ __forceinline__ float ld2f(const float* p, long i) { return p[i]; }
__device__ __forceinline__ float ld2f(const __hip_bfloat16* p, long i) { return __bfloat162float(p[i]); }

// out[C][R] = (bf16) in[R][C], batched via blockIdx.z
template <typename TIN>
__global__ __launch_bounds__(256) void k_tr(const TIN* __restrict__ in, ushort* __restrict__ out,
                                            int R, int C, long inB, long outB) {
  __shared__ float t[32][33];
  const long b = blockIdx.z;
  const TIN* ip = in + b * inB;
  ushort* op = out + b * outB;
  const int c0 = blockIdx.x << 5, r0 = blockIdx.y << 5;
  const int tx = threadIdx.x & 31, ty = threadIdx.x >> 5;  // 32x8
#pragma unroll
  for (int j = 0; j < 32; j += 8)
    t[ty + j][tx] = ld2f(ip, (long)(r0 + ty + j) * C + (c0 + tx));
  __syncthreads();
#pragma unroll
  for (int j = 0; j < 32; j += 8)
    op[(long)(c0 + ty + j) * R + (r0 + tx)] = f2b(t[tx][ty + j]);
}

__global__ __launch_bounds__(256) void k_gemm1(const ushort* __restrict__ xb,
                                               const ushort* __restrict__ w1t,
                                               const float* __restrict__ b1,
                                               ushort* __restrict__ hb) {
  __shared__ ushort smem[128 * 128];
  f32x4 acc[4][4];
  const int brow = blockIdx.x << 7, bcol = blockIdx.y << 7;
  gemm_core_128(xb, w1t, DM, brow, bcol, acc, smem);
  const int tid = threadIdx.x, w = tid >> 6, l = tid & 63;
  const int c0l = ((w & 1) << 6) + (l & 15);
  // bias + relu in acc layout (bias is per-column, 4 scalar loads)
#pragma unroll
  for (int n = 0; n < 4; n++) {
    const float bias = b1[bcol + c0l + n * 16];
#pragma unroll
    for (int m = 0; m < 4; m++)
#pragma unroll
      for (int j = 0; j < 4; j++) {
        float v = acc[m][n][j] + bias;
        acc[m][n][j] = v > 0.f ? v : 0.f;
      }
  }
  acc_to_lds_bf16(acc, smem);
  __syncthreads();
  const int rb = tid >> 4, cb = tid & 15;
#pragma unroll
  for (int i = 0; i < 8; i++) {
    const int row = i * 16 + rb;
    bf16x8 s = *(const bf16x8*)(smem + row * 128 + cb * 8);
    *(bf16x8*)(hb + (long)(brow + row) * DF + bcol + cb * 8) = s;
  }
}

__global__ __launch_bounds__(256) void k_gemm2(const ushort* __restrict__ hb,
                                               const ushort* __restrict__ w2t,
                                               const float* __restrict__ b2,
                                               ushort* __restrict__ kb,
                                               ushort* __restrict__ qb,
                                               ushort* __restrict__ vb) {
  __shared__ ushort smem[128 * 128];
  f32x4 acc[4][4];
  const int brow = blockIdx.x << 7, bcol = blockIdx.y << 7;
  gemm_core_128(hb, w2t, DF, brow, bcol, acc, smem);
  const int seg = bcol >> 9;  // 0:k 1:q 2:v (reference splits k first!)
  ushort* dst = (seg == 0) ? kb : ((seg == 1) ? qb : vb);
  const float sc = (seg == 1) ? 0.04419417382415922f : 1.0f;  // fold 1/sqrt(512) into q
  const int tid = threadIdx.x, w = tid >> 6, l = tid & 63;
  const int c0l = ((w & 1) << 6) + (l & 15);
#pragma unroll
  for (int n = 0; n < 4; n++) {
    const float bias = b2[bcol + c0l + n * 16];
#pragma unroll
    for (int m = 0; m < 4; m++)
#pragma unroll
      for (int j = 0; j < 4; j++)
        acc[m][n][j] = (acc[m][n][j] + bias) * sc;
  }
  acc_to_lds_bf16(acc, smem);
  __syncthreads();
  const int rb = tid >> 4, cb = tid & 15;
  const int clb = bcol - (seg << 9);  // tile col base within k/q/v
#pragma unroll
  for (int i = 0; i < 8; i++) {
    const int row = i * 16 + rb;
    bf16x8 s = *(const bf16x8*)(smem + row * 128 + cb * 8);
    *(bf16x8*)(dst + (long)(brow + row) * DM + clb + cb * 8) = s;
  }
}

__global__ __launch_bounds__(256) void k_qk(const ushort* __restrict__ qb,
                                            const ushort* __restrict__ kb,
                                            const float* __restrict__ mask,
                                            ushort* __restrict__ Sbuf) {
  __shared__ ushort smem[128 * 128];
  const int batch = blockIdx.z;
  const ushort* A = qb + (long)batch * NN * DM;
  const ushort* Bm = kb + (long)batch * NN * DM;
  const float* mk = mask + (long)batch * NN * NN;
  ushort* S = Sbuf + (long)batch * NN * NN;
  f32x4 acc[4][4];
  const int brow = blockIdx.x << 7, bcol = blockIdx.y << 7;
  gemm_core_128(A, Bm, DM, brow, bcol, acc, smem);
  acc_to_lds_bf16(acc, smem);
  __syncthreads();
  const int tid = threadIdx.x, rb = tid >> 4, cb = tid & 15;
#pragma unroll
  for (int i = 0; i < 8; i++) {
    const int row = i * 16 + rb;
    const long goff = (long)(brow + row) * NN + bcol + cb * 8;
    bf16x8 s = *(const bf16x8*)(smem + row * 128 + cb * 8);
    const float4 m0 = *(const float4*)(mk + goff);
    const float4 m1 = *(const float4*)(mk + goff + 4);
    bf16x8 o;
    o[0] = (short)f2b(b2f((ushort)s[0]) * m0.x);
    o[1] = (short)f2b(b2f((ushort)s[1]) * m0.y);
    o[2] = (short)f2b(b2f((ushort)s[2]) * m0.z);
    o[3] = (short)f2b(b2f((ushort)s[3]) * m0.w);
    o[4] = (short)f2b(b2f((ushort)s[4]) * m1.x);
    o[5] = (short)f2b(b2f((ushort)s[5]) * m1.y);
    o[6] = (short)f2b(b2f((ushort)s[6]) * m1.z);
    o[7] = (short)f2b(b2f((ushort)s[7]) * m1.w);
    *(bf16x8*)(S + goff) = o;
  }
}

__global__ __launch_bounds__(256) void k_pv(const ushort* __restrict__ Sbuf,
                                            const ushort* __restrict__ vtb,
                                            float* __restrict__ out) {
  __shared__ ushort smem[128 * 128];
  const int batch = blockIdx.z;
  const ushort* A = Sbuf + (long)batch * NN * NN;
  const ushort* Bm = vtb + (long)batch * DM * NN;  // v^T [512][2048]
  float* op = out + (long)batch * NN * DM;
  f32x4 acc[4][4];
  const int brow = blockIdx.x << 7, bcol = blockIdx.y << 7;
  gemm_core_128(A, Bm, NN, brow, bcol, acc, smem);
  const int tid = threadIdx.x, w = tid >> 6, l = tid & 63;
  const int r0 = brow + ((w >> 1) << 6) + ((l >> 4) << 2);
  const int c0 = bcol + ((w & 1) << 6) + (l & 15);
#pragma unroll
  for (int n = 0; n < 4; n++) {
    const int c = c0 + n * 16;
#pragma unroll
    for (int m = 0; m < 4; m++) {
      const int r = r0 + m * 16;
#pragma unroll
      for (int j = 0; j < 4; j++)
        op[(long)(r + j) * DM + c] = acc[m][n][j];
    }
  }
}

// ---------------- launch ----------------
extern "C" void kernel_launch(void* const* d_in, const int* in_sizes, int n_in,
                              void* d_out, int out_size, void* d_ws, size_t ws_size,
                              hipStream_t stream) {
  const float* x    = (const float*)d_in[0];
  const float* mask = (const float*)d_in[1];
  const float* W1   = (const float*)d_in[2];
  const float* b1   = (const float*)d_in[3];
  const float* W2   = (const float*)d_in[4];
  const float* b2   = (const float*)d_in[5];
  float* out = (float*)d_out;

  char* ws = (char*)d_ws;
  size_t off = 0;
  auto alloc = [&](size_t n) { char* p = ws + off; off += (n + 255) & ~(size_t)255; return p; };
  ushort* xb  = (ushort*)alloc((size_t)NB * NN * DM * 2);
  ushort* hb  = (ushort*)alloc((size_t)NB * NN * DF * 2);
  ushort* w1t = (ushort*)alloc((size_t)DF * DM * 2);
  ushort* w2t = (ushort*)alloc((size_t)3 * DM * DF * 2);
  ushort* kb  = (ushort*)alloc((size_t)NB * NN * DM * 2);
  ushort* qb  = (ushort*)alloc((size_t)NB * NN * DM * 2);
  ushort* vb  = (ushort*)alloc((size_t)NB * NN * DM * 2);
  ushort* vtb = (ushort*)alloc((size_t)NB * NN * DM * 2);
  ushort* Sbuf = (ushort*)alloc((size_t)NB * NN * NN * 2);  // full 8-batch S (67MB)

  // x -> bf16
  k_cvt<<<dim3(8192), dim3(256), 0, stream>>>(x, xb);
  // W1 [512,1024] -> w1t [1024,512] ; W2 [1024,1536] -> w2t [1536,1024]
  k_tr<float><<<dim3(DF / 32, DM / 32, 1), dim3(256), 0, stream>>>(W1, w1t, DM, DF, 0, 0);
  k_tr<float><<<dim3(3 * DM / 32, DF / 32, 1), dim3(256), 0, stream>>>(W2, w2t, DF, 3 * DM, 0, 0);
  // h = relu(x@W1+b1)
  k_gemm1<<<dim3(NB * NN / 128, DF / 128), dim3(256), 0, stream>>>(xb, w1t, b1, hb);
  // kqv = h@W2+b2, split (q pre-scaled)
  k_gemm2<<<dim3(NB * NN / 128, 3 * DM / 128), dim3(256), 0, stream>>>(hb, w2t, b2, kb, qb, vb);
  // v [2048,512] -> v^T [512,2048] per batch
  k_tr<__hip_bfloat16><<<dim3(DM / 32, NN / 32, NB), dim3(256), 0, stream>>>(
      (const __hip_bfloat16*)vb, vtb, NN, DM, (long)NN * DM, (long)DM * NN);
  // attention: all 8 batches in single launches
  k_qk<<<dim3(NN / 128, NN / 128, NB), dim3(256), 0, stream>>>(qb, kb, mask, Sbuf);
  k_pv<<<dim3(NN / 128, DM / 128, NB), dim3(256), 0, stream>>>(Sbuf, vtb, out);
}